// Round 9
// baseline (760.409 us; speedup 1.0000x reference)
//
#include <hip/hip_runtime.h>
#include <hip/hip_bf16.h>
#include <hip/hip_cooperative_groups.h>

namespace cg = cooperative_groups;

#define NTOKEN 150000
#define NINP   64
#define NEDGE  2400000
#define NPOS   (64*200)

#define NPB    256            // nodes per bucket (bucket = dst >> 8)
#define NBUCK  586            // ceil(NTOKEN / NPB)
#define EPB    4096           // edges per CSR block
#define NBLK   586            // ceil(NEDGE / EPB)
#define CAP    4608           // LDS edge capacity per bucket (mean 4096 + 8 sigma)
#define GRID_CSR (NBLK + 9)   // 586 CSR blocks + 8 M-blocks + 1 cvec-block

// word (4-byte) offsets into workspace
#define O_Z1       0              // f32 [150000*64]; written by k_agg (histG dead by then)
#define O_HIST     0              // i32 [NBLK*NBUCK=343396]; internal to kCSR
#define O_CTOT     9600000        // i32 [586]
#define O_DINV     9601280        // f32 [150000]
#define O_ROWSTART 9751296        // i32 [150001]
#define O_BUCK     9901312        // i32 [2400000] packed; becomes sortedSrc
#define O_M        12301312       // f32 [4096]  (W1@W2)
#define O_CVEC     12305408       // f32 [64]    (b1@W2)

// ---- One cooperative kernel: hist -> colscan -> bucket scan -> scatter -> sort ----
__global__ void __launch_bounds__(512) kCSR(
        const int* __restrict__ src, const int* __restrict__ dst,
        int* __restrict__ histG, int* __restrict__ colTotal,
        int* __restrict__ bucketPacked, float* __restrict__ dinv,
        int* __restrict__ rowStart,
        const float* __restrict__ W1, const float* __restrict__ b1,
        const float* __restrict__ W2, float* __restrict__ M,
        float* __restrict__ cvec) {
    cg::grid_group grid = cg::this_grid();
    __shared__ int bs[NBUCK + 1];
    __shared__ int smem[2 * CAP + 2 * NPB];   // 9728 ints; aliased per phase
    int* eSrc = smem;                         // [EPB]      phases 1-4
    int* eDst = smem + EPB;                   // [EPB]
    int* h    = smem + 2 * EPB;               // [NBUCK]    hist, then cursor
    int* sd   = smem + 2 * EPB + NBUCK;       // [512]      scan scratch
    int t = threadIdx.x, B = blockIdx.x;
    bool isCSR = (B < NBLK);

    // ---- Phase 1: edges -> LDS + per-block histogram; extra blocks do smallmat ----
    if (isCSR) {
        for (int i = t; i < NBUCK; i += 512) h[i] = 0;
        __syncthreads();
        int base = B * EPB;
        int n = NEDGE - base; if (n > EPB) n = EPB;      // 4096, last block 3840
        const int4* s4 = (const int4*)(src + base);
        const int4* d4 = (const int4*)(dst + base);
        for (int i = t; i < (n >> 2); i += 512) {
            int4 s = s4[i];
            int4 d = d4[i];
            eSrc[4*i+0] = s.x; eSrc[4*i+1] = s.y; eSrc[4*i+2] = s.z; eSrc[4*i+3] = s.w;
            eDst[4*i+0] = d.x; eDst[4*i+1] = d.y; eDst[4*i+2] = d.z; eDst[4*i+3] = d.w;
            atomicAdd(&h[d.x >> 8], 1);
            atomicAdd(&h[d.y >> 8], 1);
            atomicAdd(&h[d.z >> 8], 1);
            atomicAdd(&h[d.w >> 8], 1);
        }
        __syncthreads();
        for (int i = t; i < NBUCK; i += 512) histG[B * NBUCK + i] = h[i];
    } else {
        int bb = B - NBLK;
        if (bb < 8) {
            int o = bb * 512 + t;                        // [0, 4096)
            int i = o >> 6, j = o & 63;
            float s = 0.f;
            #pragma unroll 4
            for (int k = 0; k < 128; k++) s = fmaf(W1[i * 128 + k], W2[k * 64 + j], s);
            M[o] = s;
        } else if (t < 64) {
            float s = 0.f;
            #pragma unroll 4
            for (int k = 0; k < 128; k++) s = fmaf(b1[k], W2[k * 64 + t], s);
            cvec[t] = s;
        }
    }
    __threadfence();
    grid.sync();

    // ---- Phase 2: column exclusive scan over blocks; bucket b = B ----
    if (isCSR) {
        int b = B;
        int i0 = 2 * t, i1 = 2 * t + 1;
        int v0 = (i0 < NBLK) ? histG[i0 * NBUCK + b] : 0;
        int v1 = (i1 < NBLK) ? histG[i1 * NBUCK + b] : 0;
        int ts = v0 + v1;
        sd[t] = ts;
        __syncthreads();
        for (int off = 1; off < 512; off <<= 1) {
            int x = (t >= off) ? sd[t - off] : 0;
            __syncthreads();
            sd[t] += x;
            __syncthreads();
        }
        int excl = sd[t] - ts;
        if (i0 < NBLK) histG[i0 * NBUCK + b] = excl;
        if (i1 < NBLK) histG[i1 * NBUCK + b] = excl + v0;
        if (t == 511) colTotal[b] = sd[511];
    }
    __threadfence();
    grid.sync();

    // ---- Phase 3: every CSR block computes full bucketStart scan into LDS ----
    if (isCSR) {
        int i0 = 2 * t, i1 = 2 * t + 1;
        int v0 = (i0 < NBUCK) ? colTotal[i0] : 0;
        int v1 = (i1 < NBUCK) ? colTotal[i1] : 0;
        int ts = v0 + v1;
        sd[t] = ts;
        __syncthreads();
        for (int off = 1; off < 512; off <<= 1) {
            int x = (t >= off) ? sd[t - off] : 0;
            __syncthreads();
            sd[t] += x;
            __syncthreads();
        }
        int excl = sd[t] - ts;
        if (i0 < NBUCK) bs[i0] = excl;
        if (i1 < NBUCK) bs[i1] = excl + v0;
        if (t == 0) bs[NBUCK] = NEDGE;
        __syncthreads();
        // ---- Phase 4: init cursors, scatter LDS edges to global bucket regions ----
        for (int i = t; i < NBUCK; i += 512) h[i] = histG[B * NBUCK + i] + bs[i];
        __syncthreads();
        int base = B * EPB;
        int n = NEDGE - base; if (n > EPB) n = EPB;
        for (int i = t; i < n; i += 512) {
            int d = eDst[i];
            int pos = atomicAdd(&h[d >> 8], 1);
            bucketPacked[pos] = (eSrc[i] << 8) | (d & 255);
        }
    }
    __threadfence();
    grid.sync();

    // ---- Phase 5: per-bucket count+scan -> dinv/rowStart; LDS sort; coalesced dump ----
    if (isCSR) {
        int* raw = smem;                 // [CAP]
        int* srt = smem + CAP;           // [CAP]
        int* cnt = smem + 2 * CAP;       // [NPB]
        int* sd2 = smem + 2 * CAP + NPB; // [NPB]
        int b = B;
        int e0 = bs[b], e1 = bs[b + 1];
        int nE = e1 - e0;
        int nEc = (nE < CAP) ? nE : CAP;
        if (t < NPB) cnt[t] = 0;
        __syncthreads();
        for (int i = t; i < nEc; i += 512) {
            int p = bucketPacked[e0 + i];
            raw[i] = p;
            atomicAdd(&cnt[p & 255], 1);
        }
        __syncthreads();
        int c = 0;
        if (t < NPB) { c = cnt[t]; sd2[t] = c; }
        __syncthreads();
        for (int off = 1; off < 256; off <<= 1) {
            int x = 0;
            if (t < NPB && t >= off) x = sd2[t - off];
            __syncthreads();
            if (t < NPB) sd2[t] += x;
            __syncthreads();
        }
        if (t < NPB) {
            int excl = sd2[t] - c;
            cnt[t] = excl;               // becomes cursor
            int node = b * NPB + t;
            if (node < NTOKEN) {
                dinv[node] = rsqrtf((float)c + 1.0f);
                rowStart[node] = e0 + excl;
            }
            if (b == NBUCK - 1 && t == 0) rowStart[NTOKEN] = NEDGE;
        }
        __syncthreads();
        for (int i = t; i < nEc; i += 512) {
            int p = raw[i];
            int pos = atomicAdd(&cnt[p & 255], 1);
            if (pos < CAP) srt[pos] = p >> 8;
        }
        __syncthreads();
        for (int i = t; i < nEc; i += 512) bucketPacked[e0 + i] = srt[i];
    }
}

// ---- Z1s[v] = dv^2*( sum_u dinv[u]*X[u] + dv*X[v] ); 16-lane group/node, masked unroll 8 ----
__global__ void k_agg(const float4* __restrict__ X4, const float* __restrict__ dinv,
                      const int* __restrict__ rowStart, const int* __restrict__ sortedSrc,
                      float4* __restrict__ Z1s) {
    int g = threadIdx.x >> 4;           // 16 groups per block
    int fl = threadIdx.x & 15;
    int v = blockIdx.x * 16 + g;        // grid*16 == NTOKEN exactly
    int e0 = rowStart[v], e1 = rowStart[v + 1];
    float dv = dinv[v];
    float4 xs = X4[(size_t)v * 16 + fl];
    float4 a0 = {0.f,0.f,0.f,0.f}, a1 = {0.f,0.f,0.f,0.f};
    float4 a2 = {0.f,0.f,0.f,0.f}, a3 = {0.f,0.f,0.f,0.f};
    for (int e = e0; e < e1; e += 8) {
        int m1 = e + 1 < e1, m2 = e + 2 < e1, m3 = e + 3 < e1;
        int m4 = e + 4 < e1, m5 = e + 5 < e1, m6 = e + 6 < e1, m7 = e + 7 < e1;
        int u0 = sortedSrc[e];
        int u1 = sortedSrc[m1 ? e + 1 : e];
        int u2 = sortedSrc[m2 ? e + 2 : e];
        int u3 = sortedSrc[m3 ? e + 3 : e];
        int u4 = sortedSrc[m4 ? e + 4 : e];
        int u5 = sortedSrc[m5 ? e + 5 : e];
        int u6 = sortedSrc[m6 ? e + 6 : e];
        int u7 = sortedSrc[m7 ? e + 7 : e];
        float d0 = dinv[u0];
        float d1 = m1 ? dinv[u1] : 0.f;
        float d2 = m2 ? dinv[u2] : 0.f;
        float d3 = m3 ? dinv[u3] : 0.f;
        float d4 = m4 ? dinv[u4] : 0.f;
        float d5 = m5 ? dinv[u5] : 0.f;
        float d6 = m6 ? dinv[u6] : 0.f;
        float d7 = m7 ? dinv[u7] : 0.f;
        float4 x0 = X4[(size_t)u0 * 16 + fl];
        float4 x1 = X4[(size_t)u1 * 16 + fl];
        float4 x2 = X4[(size_t)u2 * 16 + fl];
        float4 x3 = X4[(size_t)u3 * 16 + fl];
        float4 x4 = X4[(size_t)u4 * 16 + fl];
        float4 x5 = X4[(size_t)u5 * 16 + fl];
        float4 x6 = X4[(size_t)u6 * 16 + fl];
        float4 x7 = X4[(size_t)u7 * 16 + fl];
        a0.x = fmaf(d0, x0.x, a0.x); a0.y = fmaf(d0, x0.y, a0.y);
        a0.z = fmaf(d0, x0.z, a0.z); a0.w = fmaf(d0, x0.w, a0.w);
        a1.x = fmaf(d1, x1.x, a1.x); a1.y = fmaf(d1, x1.y, a1.y);
        a1.z = fmaf(d1, x1.z, a1.z); a1.w = fmaf(d1, x1.w, a1.w);
        a2.x = fmaf(d2, x2.x, a2.x); a2.y = fmaf(d2, x2.y, a2.y);
        a2.z = fmaf(d2, x2.z, a2.z); a2.w = fmaf(d2, x2.w, a2.w);
        a3.x = fmaf(d3, x3.x, a3.x); a3.y = fmaf(d3, x3.y, a3.y);
        a3.z = fmaf(d3, x3.z, a3.z); a3.w = fmaf(d3, x3.w, a3.w);
        a0.x = fmaf(d4, x4.x, a0.x); a0.y = fmaf(d4, x4.y, a0.y);
        a0.z = fmaf(d4, x4.z, a0.z); a0.w = fmaf(d4, x4.w, a0.w);
        a1.x = fmaf(d5, x5.x, a1.x); a1.y = fmaf(d5, x5.y, a1.y);
        a1.z = fmaf(d5, x5.z, a1.z); a1.w = fmaf(d5, x5.w, a1.w);
        a2.x = fmaf(d6, x6.x, a2.x); a2.y = fmaf(d6, x6.y, a2.y);
        a2.z = fmaf(d6, x6.z, a2.z); a2.w = fmaf(d6, x6.w, a2.w);
        a3.x = fmaf(d7, x7.x, a3.x); a3.y = fmaf(d7, x7.y, a3.y);
        a3.z = fmaf(d7, x7.z, a3.z); a3.w = fmaf(d7, x7.w, a3.w);
    }
    float ax = (a0.x + a1.x) + (a2.x + a3.x);
    float ay = (a0.y + a1.y) + (a2.y + a3.y);
    float az = (a0.z + a1.z) + (a2.z + a3.z);
    float aw = (a0.w + a1.w) + (a2.w + a3.w);
    float c = dv * dv;
    float4 o;
    o.x = c * fmaf(dv, xs.x, ax);
    o.y = c * fmaf(dv, xs.y, ay);
    o.z = c * fmaf(dv, xs.z, az);
    o.w = c * fmaf(dv, xs.w, aw);
    Z1s[(size_t)v * 16 + fl] = o;
}

// ---- out[p] = z2 @ M + s*cvec + b2 ----
__global__ void k_out(const int* __restrict__ inp, const float4* __restrict__ Z1s,
                      const float* __restrict__ dinv, const int* __restrict__ rowStart,
                      const int* __restrict__ sortedSrc, const float* __restrict__ M,
                      const float* __restrict__ cvec, const float* __restrict__ b2,
                      float* __restrict__ out) {
    int wid = threadIdx.x >> 6;
    int lane = threadIdx.x & 63;
    int g = lane >> 4, fl = lane & 15;
    int p = blockIdx.x * 4 + wid;
    if (p >= NPOS) return;
    int v = inp[p];
    int e0 = rowStart[v], e1 = rowStart[v + 1];
    float ax0 = 0.f, ay0 = 0.f, az0 = 0.f, aw0 = 0.f, ss0 = 0.f;
    float ax1 = 0.f, ay1 = 0.f, az1 = 0.f, aw1 = 0.f, ss1 = 0.f;
    int e = e0 + g;
    for (; e + 4 < e1; e += 8) {
        int u0 = sortedSrc[e];
        int u1 = sortedSrc[e + 4];
        ss0 += dinv[u0]; ss1 += dinv[u1];
        float4 z0 = Z1s[(size_t)u0 * 16 + fl];
        float4 z1 = Z1s[(size_t)u1 * 16 + fl];
        ax0 += z0.x; ay0 += z0.y; az0 += z0.z; aw0 += z0.w;
        ax1 += z1.x; ay1 += z1.y; az1 += z1.z; aw1 += z1.w;
    }
    if (e < e1) {
        int u = sortedSrc[e];
        ss0 += dinv[u];
        float4 z = Z1s[(size_t)u * 16 + fl];
        ax0 += z.x; ay0 += z.y; az0 += z.z; aw0 += z.w;
    }
    float ax = ax0 + ax1, ay = ay0 + ay1, az = az0 + az1, aw = aw0 + aw1, ss = ss0 + ss1;
    ax += __shfl_xor(ax, 16, 64); ay += __shfl_xor(ay, 16, 64);
    az += __shfl_xor(az, 16, 64); aw += __shfl_xor(aw, 16, 64);
    ss += __shfl_xor(ss, 16, 64);
    ax += __shfl_xor(ax, 32, 64); ay += __shfl_xor(ay, 32, 64);
    az += __shfl_xor(az, 32, 64); aw += __shfl_xor(aw, 32, 64);
    ss += __shfl_xor(ss, 32, 64);
    float dv = dinv[v];
    float4 zs = Z1s[(size_t)v * 16 + fl];
    float z2x = dv * (ax + zs.x);
    float z2y = dv * (ay + zs.y);
    float z2z = dv * (az + zs.z);
    float z2w = dv * (aw + zs.w);
    float s = dv * (ss + dv);
    float o = fmaf(s, cvec[lane], b2[lane]);
    #pragma unroll
    for (int kb = 0; kb < 16; kb++) {
        float a0 = __shfl(z2x, kb, 64);
        float a1 = __shfl(z2y, kb, 64);
        float a2 = __shfl(z2z, kb, 64);
        float a3 = __shfl(z2w, kb, 64);
        o = fmaf(a0, M[(kb * 4 + 0) * 64 + lane], o);
        o = fmaf(a1, M[(kb * 4 + 1) * 64 + lane], o);
        o = fmaf(a2, M[(kb * 4 + 2) * 64 + lane], o);
        o = fmaf(a3, M[(kb * 4 + 3) * 64 + lane], o);
    }
    out[(size_t)p * 64 + lane] = o;
}

extern "C" void kernel_launch(void* const* d_in, const int* in_sizes, int n_in,
                              void* d_out, int out_size, void* d_ws, size_t ws_size,
                              hipStream_t stream) {
    const float* emb = (const float*)d_in[0];
    const float* W1  = (const float*)d_in[1];
    const float* b1  = (const float*)d_in[2];
    const float* W2  = (const float*)d_in[3];
    const float* b2  = (const float*)d_in[4];
    const int*   inp = (const int*)d_in[5];
    // d_in[6] = input_timestamp (unused by the reference)
    const int*   ei  = (const int*)d_in[7];
    const int* srcArr = ei;
    const int* dstArr = ei + NEDGE;
    float* out = (float*)d_out;

    float* ws         = (float*)d_ws;
    float* Z1s        = ws + O_Z1;
    int*   histG      = (int*)ws + O_HIST;
    int*   colTotal   = (int*)ws + O_CTOT;
    float* dinv       = ws + O_DINV;
    int*   rowStart   = (int*)ws + O_ROWSTART;
    int*   buckPacked = (int*)ws + O_BUCK;     // becomes sortedSrc after kCSR
    float* M          = ws + O_M;
    float* cvec       = ws + O_CVEC;

    void* args[12] = {
        (void*)&srcArr, (void*)&dstArr, (void*)&histG, (void*)&colTotal,
        (void*)&buckPacked, (void*)&dinv, (void*)&rowStart,
        (void*)&W1, (void*)&b1, (void*)&W2, (void*)&M, (void*)&cvec
    };
    hipLaunchCooperativeKernel((const void*)kCSR, dim3(GRID_CSR), dim3(512),
                               args, 0, stream);

    k_agg <<<NTOKEN/16, 256, 0, stream>>>((const float4*)emb, dinv, rowStart,
                                          buckPacked, (float4*)Z1s);
    k_out <<<NPOS/4, 256, 0, stream>>>(inp, (const float4*)Z1s, dinv, rowStart,
                                       buckPacked, M, cvec, b2, out);
}

// Round 10
// 133.171 us; speedup vs baseline: 5.7100x; 5.7100x over previous
//
#include <hip/hip_runtime.h>
#include <hip/hip_bf16.h>

#define NTOKEN 150000
#define NINP   64
#define NEDGE  2400000
#define NPOS   (64*200)

#define NPB    256            // nodes per bucket (bucket = dst >> 8)
#define NBUCK  586            // ceil(NTOKEN / NPB)
#define EPB    8192           // edges per block in kA/kC
#define NBLK   293            // ceil(NEDGE / EPB)
#define CAP    6144           // LDS edge capacity per bucket (mean 4096 + slack)

// word (4-byte) offsets into workspace (total ~49.2 MiB, unchanged)
#define O_Z1       0              // bf16 [150000*64] = 4.8M words; written by k_agg
#define O_HIST     0              // i32 [NBLK*NBUCK=171698]; dead before k_agg writes Z1
#define O_XBF      4800000        // bf16 [150000*64] = 4.8M words; written by kX
#define O_CTOT     9600000        // i32 [586]
#define O_BSTART   9600640        // i32 [587]
#define O_DINV     9601280        // f32 [150000]
#define O_ROWSTART 9751296        // i32 [150001]
#define O_BUCK     9901312        // i32 [2400000] packed; sorted in place by kDE
#define O_M        12301312       // f32 [4096]  (W1@W2)
#define O_CVEC     12305408       // f32 [64]    (b1@W2)

__device__ __forceinline__ unsigned f2bf(float f) {
    unsigned u = __float_as_uint(f);
    return (u + 0x7FFFu + ((u >> 16) & 1u)) >> 16;   // RTN-even
}

// ---- Pass X: emb f32 -> bf16 (RTN); 8 elems/thread ----
__global__ void kX(const float4* __restrict__ X4, uint4* __restrict__ Xbf) {
    int i = blockIdx.x * 256 + threadIdx.x;
    if (i >= NTOKEN * 64 / 8) return;
    float4 a = X4[2 * i], b = X4[2 * i + 1];
    uint4 o;
    o.x = f2bf(a.x) | (f2bf(a.y) << 16);
    o.y = f2bf(a.z) | (f2bf(a.w) << 16);
    o.z = f2bf(b.x) | (f2bf(b.y) << 16);
    o.w = f2bf(b.z) | (f2bf(b.w) << 16);
    Xbf[i] = o;
}

// ---- Pass A: per-block bucket histogram (LDS atomics only), int4 edge reads ----
__global__ void kA_hist(const int4* __restrict__ dst4, int* __restrict__ histG) {
    __shared__ int h[NBUCK];
    int tid = threadIdx.x;
    for (int i = tid; i < NBUCK; i += 1024) h[i] = 0;
    __syncthreads();
    int base4 = blockIdx.x * (EPB / 4);
    #pragma unroll
    for (int i = 0; i < EPB / 4096; i++) {
        int idx = base4 + i * 1024 + tid;
        if (idx < NEDGE / 4) {
            int4 d = dst4[idx];
            atomicAdd(&h[d.x >> 8], 1);
            atomicAdd(&h[d.y >> 8], 1);
            atomicAdd(&h[d.z >> 8], 1);
            atomicAdd(&h[d.w >> 8], 1);
        }
    }
    __syncthreads();
    for (int i = tid; i < NBUCK; i += 1024) histG[blockIdx.x * NBUCK + i] = h[i];
}

// ---- Pass B1: per-bucket column exclusive scan over blocks ----
__global__ void kB1_colscan(int* __restrict__ histG, int* __restrict__ colTotal) {
    __shared__ int sd[256];
    int t = threadIdx.x, b = blockIdx.x;
    int i0 = 2 * t, i1 = 2 * t + 1;
    int v0 = (i0 < NBLK) ? histG[i0 * NBUCK + b] : 0;
    int v1 = (i1 < NBLK) ? histG[i1 * NBUCK + b] : 0;
    int tsum = v0 + v1;
    sd[t] = tsum;
    __syncthreads();
    for (int off = 1; off < 256; off <<= 1) {
        int x = (t >= off) ? sd[t - off] : 0;
        __syncthreads();
        sd[t] += x;
        __syncthreads();
    }
    int excl = sd[t] - tsum;
    if (i0 < NBLK) histG[i0 * NBUCK + b] = excl;
    if (i1 < NBLK) histG[i1 * NBUCK + b] = excl + v0;
    if (t == 255) colTotal[b] = sd[255];
}

// ---- Pass B2 (+smallmat): block 0 = bucket scan; 1..16 = M; 17 = cvec ----
__global__ void kB2s(const int* __restrict__ colTotal, int* __restrict__ bucketStart,
                     const float* __restrict__ W1, const float* __restrict__ b1,
                     const float* __restrict__ W2,
                     float* __restrict__ M, float* __restrict__ cvec) {
    int bb = blockIdx.x;
    int t = threadIdx.x;
    if (bb == 0) {
        __shared__ int sd[256];
        int i0 = t * 3, i1 = t * 3 + 1, i2 = t * 3 + 2;
        int v0 = (i0 < NBUCK) ? colTotal[i0] : 0;
        int v1 = (i1 < NBUCK) ? colTotal[i1] : 0;
        int v2 = (i2 < NBUCK) ? colTotal[i2] : 0;
        int tsum = v0 + v1 + v2;
        sd[t] = tsum;
        __syncthreads();
        for (int off = 1; off < 256; off <<= 1) {
            int x = (t >= off) ? sd[t - off] : 0;
            __syncthreads();
            sd[t] += x;
            __syncthreads();
        }
        int excl = sd[t] - tsum;
        if (i0 < NBUCK) bucketStart[i0] = excl;
        if (i1 < NBUCK) bucketStart[i1] = excl + v0;
        if (i2 < NBUCK) bucketStart[i2] = excl + v0 + v1;
        if (t == 255) bucketStart[NBUCK] = NEDGE;
    } else if (bb <= 16) {
        int o = (bb - 1) * 256 + t;
        int i = o >> 6, j = o & 63;
        float s = 0.f;
        #pragma unroll 4
        for (int k = 0; k < 128; k++) s = fmaf(W1[i * 128 + k], W2[k * 64 + j], s);
        M[o] = s;
    } else if (t < 64) {
        float s = 0.f;
        #pragma unroll 4
        for (int k = 0; k < 128; k++) s = fmaf(b1[k], W2[k * 64 + t], s);
        cvec[t] = s;
    }
}

// ---- Pass C: scatter edges into bucket regions (LDS cursors), int4 edge reads ----
__global__ void kC_scatter(const int4* __restrict__ src4, const int4* __restrict__ dst4,
                           const int* __restrict__ histG, const int* __restrict__ bucketStart,
                           int* __restrict__ bucketPacked) {
    __shared__ int cur[NBUCK];
    int tid = threadIdx.x;
    for (int i = tid; i < NBUCK; i += 1024)
        cur[i] = histG[blockIdx.x * NBUCK + i] + bucketStart[i];
    __syncthreads();
    int base4 = blockIdx.x * (EPB / 4);
    #pragma unroll
    for (int i = 0; i < EPB / 4096; i++) {
        int idx = base4 + i * 1024 + tid;
        if (idx < NEDGE / 4) {
            int4 s = src4[idx];
            int4 d = dst4[idx];
            int p0 = atomicAdd(&cur[d.x >> 8], 1);
            bucketPacked[p0] = (s.x << 8) | (d.x & 255);
            int p1 = atomicAdd(&cur[d.y >> 8], 1);
            bucketPacked[p1] = (s.y << 8) | (d.y & 255);
            int p2 = atomicAdd(&cur[d.z >> 8], 1);
            bucketPacked[p2] = (s.z << 8) | (d.z & 255);
            int p3 = atomicAdd(&cur[d.w >> 8], 1);
            bucketPacked[p3] = (s.w << 8) | (d.w & 255);
        }
    }
}

// ---- Pass DE: per-bucket count+scan -> dinv/rowStart; LDS sort; coalesced dump ----
__global__ void kDE(const int* __restrict__ bucketStart,
                    int* __restrict__ bucketPacked /* in: packed; out: sortedSrc */,
                    float* __restrict__ dinv, int* __restrict__ rowStart) {
    __shared__ int raw[CAP];
    __shared__ int srt[CAP];
    __shared__ int cnt[NPB];
    __shared__ int sd[NPB];
    int t = threadIdx.x, b = blockIdx.x;
    int e0 = bucketStart[b], e1 = bucketStart[b + 1];
    int nE = e1 - e0;
    int nEc = (nE < CAP) ? nE : CAP;
    if (t < NPB) cnt[t] = 0;
    __syncthreads();
    for (int i = t; i < nEc; i += 1024) {
        int p = bucketPacked[e0 + i];
        raw[i] = p;
        atomicAdd(&cnt[p & 255], 1);
    }
    __syncthreads();
    int c = 0;
    if (t < NPB) { c = cnt[t]; sd[t] = c; }
    __syncthreads();
    for (int off = 1; off < 256; off <<= 1) {
        int x = 0;
        if (t < NPB && t >= off) x = sd[t - off];
        __syncthreads();
        if (t < NPB) sd[t] += x;
        __syncthreads();
    }
    if (t < NPB) {
        int excl = sd[t] - c;
        cnt[t] = excl;                    // becomes cursor
        int node = b * NPB + t;
        if (node < NTOKEN) {
            dinv[node] = rsqrtf((float)c + 1.0f);
            rowStart[node] = e0 + excl;
        }
        if (b == NBUCK - 1 && t == 0) rowStart[NTOKEN] = NEDGE;
    }
    __syncthreads();
    for (int i = t; i < nEc; i += 1024) {
        int p = raw[i];
        int pos = atomicAdd(&cnt[p & 255], 1);
        if (pos < CAP) srt[pos] = p >> 8;
    }
    __syncthreads();
    for (int i = t; i < nEc; i += 1024) bucketPacked[e0 + i] = srt[i];
}

// ---- Z1s[v] = dv^2*( sum_u dinv[u]*X[u] + dv*X[v] ); bf16 rows (uint2/lane), unroll 8 ----
__global__ void k_agg(const uint2* __restrict__ Xb, const float* __restrict__ dinv,
                      const int* __restrict__ rowStart, const int* __restrict__ sortedSrc,
                      uint2* __restrict__ Z1b) {
    int g = threadIdx.x >> 4;           // 16 groups per block
    int fl = threadIdx.x & 15;
    int v = blockIdx.x * 16 + g;        // grid*16 == NTOKEN exactly
    int e0 = rowStart[v], e1 = rowStart[v + 1];
    float dv = dinv[v];
    uint2 xsw = Xb[(size_t)v * 16 + fl];
    float a0x=0.f,a0y=0.f,a0z=0.f,a0w=0.f, a1x=0.f,a1y=0.f,a1z=0.f,a1w=0.f;
    float a2x=0.f,a2y=0.f,a2z=0.f,a2w=0.f, a3x=0.f,a3y=0.f,a3z=0.f,a3w=0.f;
    for (int e = e0; e < e1; e += 8) {
        int m1=e+1<e1, m2=e+2<e1, m3=e+3<e1, m4=e+4<e1, m5=e+5<e1, m6=e+6<e1, m7=e+7<e1;
        int u0 = sortedSrc[e];
        int u1 = sortedSrc[m1 ? e+1 : e];
        int u2 = sortedSrc[m2 ? e+2 : e];
        int u3 = sortedSrc[m3 ? e+3 : e];
        int u4 = sortedSrc[m4 ? e+4 : e];
        int u5 = sortedSrc[m5 ? e+5 : e];
        int u6 = sortedSrc[m6 ? e+6 : e];
        int u7 = sortedSrc[m7 ? e+7 : e];
        float d0 = dinv[u0];
        float d1 = m1 ? dinv[u1] : 0.f;
        float d2 = m2 ? dinv[u2] : 0.f;
        float d3 = m3 ? dinv[u3] : 0.f;
        float d4 = m4 ? dinv[u4] : 0.f;
        float d5 = m5 ? dinv[u5] : 0.f;
        float d6 = m6 ? dinv[u6] : 0.f;
        float d7 = m7 ? dinv[u7] : 0.f;
        uint2 w0 = Xb[(size_t)u0 * 16 + fl];
        uint2 w1 = Xb[(size_t)u1 * 16 + fl];
        uint2 w2 = Xb[(size_t)u2 * 16 + fl];
        uint2 w3 = Xb[(size_t)u3 * 16 + fl];
        uint2 w4 = Xb[(size_t)u4 * 16 + fl];
        uint2 w5 = Xb[(size_t)u5 * 16 + fl];
        uint2 w6 = Xb[(size_t)u6 * 16 + fl];
        uint2 w7 = Xb[(size_t)u7 * 16 + fl];
        #define ACC(d,w,AX,AY,AZ,AW) \
            AX = fmaf(d, __uint_as_float((w).x << 16), AX); \
            AY = fmaf(d, __uint_as_float((w).x & 0xFFFF0000u), AY); \
            AZ = fmaf(d, __uint_as_float((w).y << 16), AZ); \
            AW = fmaf(d, __uint_as_float((w).y & 0xFFFF0000u), AW);
        ACC(d0,w0,a0x,a0y,a0z,a0w)
        ACC(d1,w1,a1x,a1y,a1z,a1w)
        ACC(d2,w2,a2x,a2y,a2z,a2w)
        ACC(d3,w3,a3x,a3y,a3z,a3w)
        ACC(d4,w4,a0x,a0y,a0z,a0w)
        ACC(d5,w5,a1x,a1y,a1z,a1w)
        ACC(d6,w6,a2x,a2y,a2z,a2w)
        ACC(d7,w7,a3x,a3y,a3z,a3w)
        #undef ACC
    }
    float ax = (a0x + a1x) + (a2x + a3x);
    float ay = (a0y + a1y) + (a2y + a3y);
    float az = (a0z + a1z) + (a2z + a3z);
    float aw = (a0w + a1w) + (a2w + a3w);
    float c = dv * dv;
    float ox = c * fmaf(dv, __uint_as_float(xsw.x << 16),        ax);
    float oy = c * fmaf(dv, __uint_as_float(xsw.x & 0xFFFF0000u), ay);
    float oz = c * fmaf(dv, __uint_as_float(xsw.y << 16),        az);
    float ow = c * fmaf(dv, __uint_as_float(xsw.y & 0xFFFF0000u), aw);
    uint2 o;
    o.x = f2bf(ox) | (f2bf(oy) << 16);
    o.y = f2bf(oz) | (f2bf(ow) << 16);
    Z1b[(size_t)v * 16 + fl] = o;
}

// ---- out[p] = z2 @ M + s*cvec + b2 ; Z1s gathered as bf16 ----
__global__ void k_out(const int* __restrict__ inp, const uint2* __restrict__ Z1b,
                      const float* __restrict__ dinv, const int* __restrict__ rowStart,
                      const int* __restrict__ sortedSrc, const float* __restrict__ M,
                      const float* __restrict__ cvec, const float* __restrict__ b2,
                      float* __restrict__ out) {
    int wid = threadIdx.x >> 6;
    int lane = threadIdx.x & 63;
    int g = lane >> 4, fl = lane & 15;
    int p = blockIdx.x * 4 + wid;
    if (p >= NPOS) return;
    int v = inp[p];
    int e0 = rowStart[v], e1 = rowStart[v + 1];
    float ax0=0.f,ay0=0.f,az0=0.f,aw0=0.f,ss0=0.f;
    float ax1=0.f,ay1=0.f,az1=0.f,aw1=0.f,ss1=0.f;
    int e = e0 + g;
    for (; e + 4 < e1; e += 8) {
        int u0 = sortedSrc[e];
        int u1 = sortedSrc[e + 4];
        ss0 += dinv[u0]; ss1 += dinv[u1];
        uint2 z0 = Z1b[(size_t)u0 * 16 + fl];
        uint2 z1 = Z1b[(size_t)u1 * 16 + fl];
        ax0 += __uint_as_float(z0.x << 16);
        ay0 += __uint_as_float(z0.x & 0xFFFF0000u);
        az0 += __uint_as_float(z0.y << 16);
        aw0 += __uint_as_float(z0.y & 0xFFFF0000u);
        ax1 += __uint_as_float(z1.x << 16);
        ay1 += __uint_as_float(z1.x & 0xFFFF0000u);
        az1 += __uint_as_float(z1.y << 16);
        aw1 += __uint_as_float(z1.y & 0xFFFF0000u);
    }
    if (e < e1) {
        int u = sortedSrc[e];
        ss0 += dinv[u];
        uint2 z = Z1b[(size_t)u * 16 + fl];
        ax0 += __uint_as_float(z.x << 16);
        ay0 += __uint_as_float(z.x & 0xFFFF0000u);
        az0 += __uint_as_float(z.y << 16);
        aw0 += __uint_as_float(z.y & 0xFFFF0000u);
    }
    float ax = ax0 + ax1, ay = ay0 + ay1, az = az0 + az1, aw = aw0 + aw1, ss = ss0 + ss1;
    ax += __shfl_xor(ax, 16, 64); ay += __shfl_xor(ay, 16, 64);
    az += __shfl_xor(az, 16, 64); aw += __shfl_xor(aw, 16, 64);
    ss += __shfl_xor(ss, 16, 64);
    ax += __shfl_xor(ax, 32, 64); ay += __shfl_xor(ay, 32, 64);
    az += __shfl_xor(az, 32, 64); aw += __shfl_xor(aw, 32, 64);
    ss += __shfl_xor(ss, 32, 64);
    float dv = dinv[v];
    uint2 zs = Z1b[(size_t)v * 16 + fl];
    float z2x = dv * (ax + __uint_as_float(zs.x << 16));
    float z2y = dv * (ay + __uint_as_float(zs.x & 0xFFFF0000u));
    float z2z = dv * (az + __uint_as_float(zs.y << 16));
    float z2w = dv * (aw + __uint_as_float(zs.y & 0xFFFF0000u));
    float s = dv * (ss + dv);
    float o = fmaf(s, cvec[lane], b2[lane]);
    #pragma unroll
    for (int kb = 0; kb < 16; kb++) {
        float a0 = __shfl(z2x, kb, 64);
        float a1 = __shfl(z2y, kb, 64);
        float a2 = __shfl(z2z, kb, 64);
        float a3 = __shfl(z2w, kb, 64);
        o = fmaf(a0, M[(kb * 4 + 0) * 64 + lane], o);
        o = fmaf(a1, M[(kb * 4 + 1) * 64 + lane], o);
        o = fmaf(a2, M[(kb * 4 + 2) * 64 + lane], o);
        o = fmaf(a3, M[(kb * 4 + 3) * 64 + lane], o);
    }
    out[(size_t)p * 64 + lane] = o;
}

extern "C" void kernel_launch(void* const* d_in, const int* in_sizes, int n_in,
                              void* d_out, int out_size, void* d_ws, size_t ws_size,
                              hipStream_t stream) {
    const float* emb = (const float*)d_in[0];
    const float* W1  = (const float*)d_in[1];
    const float* b1  = (const float*)d_in[2];
    const float* W2  = (const float*)d_in[3];
    const float* b2  = (const float*)d_in[4];
    const int*   inp = (const int*)d_in[5];
    // d_in[6] = input_timestamp (unused by the reference)
    const int*   ei  = (const int*)d_in[7];
    const int* srcArr = ei;
    const int* dstArr = ei + NEDGE;
    float* out = (float*)d_out;

    float* ws         = (float*)d_ws;
    uint2* Z1b        = (uint2*)(ws + O_Z1);
    int*   histG      = (int*)ws + O_HIST;
    uint2* Xbf        = (uint2*)(ws + O_XBF);
    int*   colTotal   = (int*)ws + O_CTOT;
    int*   bucketStart= (int*)ws + O_BSTART;
    float* dinv       = ws + O_DINV;
    int*   rowStart   = (int*)ws + O_ROWSTART;
    int*   buckPacked = (int*)ws + O_BUCK;     // becomes sortedSrc after kDE
    float* M          = ws + O_M;
    float* cvec       = ws + O_CVEC;

    kX         <<<(NTOKEN*64/8 + 255)/256, 256, 0, stream>>>((const float4*)emb, (uint4*)Xbf);
    kA_hist    <<<NBLK,  1024, 0, stream>>>((const int4*)dstArr, histG);
    kB1_colscan<<<NBUCK, 256,  0, stream>>>(histG, colTotal);
    kB2s       <<<18,    256,  0, stream>>>(colTotal, bucketStart, W1, b1, W2, M, cvec);
    kC_scatter <<<NBLK,  1024, 0, stream>>>((const int4*)srcArr, (const int4*)dstArr,
                                            histG, bucketStart, buckPacked);
    kDE        <<<NBUCK, 1024, 0, stream>>>(bucketStart, buckPacked, dinv, rowStart);
    k_agg      <<<NTOKEN/16, 256, 0, stream>>>(Xbf, dinv, rowStart, buckPacked, Z1b);
    k_out      <<<NPOS/4, 256, 0, stream>>>(inp, Z1b, dinv, rowStart,
                                            buckPacked, M, cvec, b2, out);
}